// Round 3
// baseline (702.752 us; speedup 1.0000x reference)
//
#include <hip/hip_runtime.h>

// ConfusionAwareFocalLoss: N=1048576 rows, C=128 classes, gamma=2, smoothing=0.1
// loss_i = cw[t] * sum_j -(1-p_j)^2 * (0.1/128 + 0.9*[j==t]) * logp_j
//        + sum_j max(P[t,j]-1, 0) * p_j          (P diag == 1 -> term 0)
// out = mean_i loss_i
//
// R3 == R2 resubmit (previous round died to container infra, no measurement).
// Design: MLP fix. R1's prefetch was void: (a) P-row loads issued AFTER the
// input prefetch meant waiting on them drained vmcnt to ~0; (b) the A=An
// rotation consumed the prefetch in the slot it was issued. Now: 4-deep
// modulo-scheduled prefetch (no copies; slot k consumes buffer k%4 and
// re-issues it for k+4), scatter loads issued BEFORE the stream so counted
// vmcnt leaves inputs in flight, and DPP row_ror reductions (VALU pipe)
// replace ds_swizzle shuffle chains (~120cy each).

#define NROWS 1048576
#define NCLS  128
#define BLOCK 256
#define GRID  4096

#define WPB    (BLOCK / 64)          // waves per block = 4
#define NWAVES (GRID * WPB)          // 16384
#define NQUADS (NROWS / 4)           // 262144 (4 rows per wave-iteration)
#define QPW    (NQUADS / NWAVES)     // 16 slots per wave, exact

constexpr float SMOOTH_OFF = 0.1f / 128.0f;
constexpr float SMOOTH_ON  = 0.9f;   // extra weight on the target column

using f4 = __attribute__((ext_vector_type(4))) float;

// ---- DPP all-reduce within each 16-lane row-group (VALU pipe, no LDS) ----
// row_ror:N ctrl = 0x120|N; rotate within the 16-lane DPP row. 8/4/2/1
// circulant doubling leaves every lane holding the full 16-lane reduction.
template <int CTRL>
__device__ __forceinline__ float row_rot(float v) {
    int r = __builtin_amdgcn_update_dpp(__float_as_int(v), __float_as_int(v),
                                        CTRL, 0xF, 0xF, false);
    return __int_as_float(r);
}
__device__ __forceinline__ float grpmax16(float v) {
    v = fmaxf(v, row_rot<0x128>(v));   // row_ror:8
    v = fmaxf(v, row_rot<0x124>(v));   // row_ror:4
    v = fmaxf(v, row_rot<0x122>(v));   // row_ror:2
    v = fmaxf(v, row_rot<0x121>(v));   // row_ror:1
    return v;
}
__device__ __forceinline__ float grpsum16(float v) {
    v += row_rot<0x128>(v);
    v += row_rot<0x124>(v);
    v += row_rot<0x122>(v);
    v += row_rot<0x121>(v);
    return v;
}

// One slot: consume (A,B,t) for its quad and (if PRE) immediately re-issue
// the same buffer for quad `qpre` (distance-4 prefetch; regalloc renames the
// old values — no wait, no copies). Scatter loads go FIRST so their vmcnt
// wait leaves the streaming loads outstanding.
template <bool PRE>
__device__ __forceinline__ float do_slot(
    f4& A, f4& B, int& t, int qpre,
    const f4* __restrict__ in4, const int* __restrict__ targets,
    const float* __restrict__ cls_w, const float* __restrict__ P,
    int lane, int g, int q16, int jb)
{
    // L2-resident scatter loads for the CURRENT target (issued first)
    const float cw = cls_w[t];
    const f4* prow = reinterpret_cast<const f4*>(P + (size_t)t * NCLS);
    const f4 pa = prow[2 * q16];
    const f4 pb = prow[2 * q16 + 1];

    const f4  Ac = A;            // renames only — no instructions
    const f4  Bc = B;
    const int tc = t;

    if (PRE) {                   // distance-4 streaming prefetch into this buffer
        A = __builtin_nontemporal_load(in4 + (size_t)qpre * 128 + lane * 2);
        B = __builtin_nontemporal_load(in4 + (size_t)qpre * 128 + lane * 2 + 1);
        t = targets[qpre * 4 + g];
    }

    // row max over 128 = 16 lanes x 8 elems (one DPP chain serves all 4 rows)
    float m = fmaxf(fmaxf(fmaxf(Ac[0], Ac[1]), fmaxf(Ac[2], Ac[3])),
                    fmaxf(fmaxf(Bc[0], Bc[1]), fmaxf(Bc[2], Bc[3])));
    m = grpmax16(m);

    float ev[8];
    #pragma unroll
    for (int k = 0; k < 4; ++k) ev[k]     = __expf(Ac[k] - m);
    #pragma unroll
    for (int k = 0; k < 4; ++k) ev[4 + k] = __expf(Bc[k] - m);

    float z = ((ev[0] + ev[1]) + (ev[2] + ev[3]))
            + ((ev[4] + ev[5]) + (ev[6] + ev[7]));
    z = grpsum16(z);

    const float mlz = m + __logf(z);     // x - mlz = log_softmax
    const float rZ  = 1.0f / z;

    float s1 = 0.0f, te = 0.0f, pen = 0.0f;
    #pragma unroll
    for (int k = 0; k < 8; ++k) {
        const float x   = (k < 4) ? Ac[k] : Bc[k - 4];
        const float pvk = (k < 4) ? pa[k] : pb[k - 4];
        const float lp  = x - mlz;           // log prob
        const float p   = ev[k] * rZ;        // prob
        const float om  = 1.0f - p;
        const float fl  = om * om * lp;      // focal-weighted log prob
        s1  += fl;
        if (jb + k == tc) te = fl;           // target column
        pen += fmaxf(pvk - 1.0f, 0.0f) * p;  // confusion penalty
    }
    return pen - cw * (SMOOTH_OFF * s1 + SMOOTH_ON * te);
}

__global__ __launch_bounds__(BLOCK) void focal_main(
    const float* __restrict__ inputs,     // [N, 128]
    const int*   __restrict__ targets,    // [N]
    const float* __restrict__ cls_w,      // [128]
    const float* __restrict__ P,          // [128, 128]
    float*       __restrict__ partial)    // [GRID]
{
    const int tid  = threadIdx.x;
    const int lane = tid & 63;
    const int wib  = tid >> 6;            // wave in block (0..3)
    const int g    = lane >> 4;           // row within quad (0..3)
    const int q16  = lane & 15;           // lane within 16-lane row-group
    const int jb   = q16 * 8;             // first class index this lane owns

    const int waveId = blockIdx.x * WPB + wib;
    const f4* in4 = reinterpret_cast<const f4*>(inputs);

    const int qb = waveId * QPW;          // contiguous 16-quad range per wave

    // prologue: fill the 4-deep pipeline (8 KiB + 4 target words in flight)
    f4 A0 = __builtin_nontemporal_load(in4 + (size_t)(qb + 0) * 128 + lane * 2);
    f4 B0 = __builtin_nontemporal_load(in4 + (size_t)(qb + 0) * 128 + lane * 2 + 1);
    f4 A1 = __builtin_nontemporal_load(in4 + (size_t)(qb + 1) * 128 + lane * 2);
    f4 B1 = __builtin_nontemporal_load(in4 + (size_t)(qb + 1) * 128 + lane * 2 + 1);
    f4 A2 = __builtin_nontemporal_load(in4 + (size_t)(qb + 2) * 128 + lane * 2);
    f4 B2 = __builtin_nontemporal_load(in4 + (size_t)(qb + 2) * 128 + lane * 2 + 1);
    f4 A3 = __builtin_nontemporal_load(in4 + (size_t)(qb + 3) * 128 + lane * 2);
    f4 B3 = __builtin_nontemporal_load(in4 + (size_t)(qb + 3) * 128 + lane * 2 + 1);
    int t0 = targets[(qb + 0) * 4 + g];
    int t1 = targets[(qb + 1) * 4 + g];
    int t2 = targets[(qb + 2) * 4 + g];
    int t3 = targets[(qb + 3) * 4 + g];

    float acc = 0.0f;

    // 12 slots with distance-4 prefetch, then 4 peeled slots (no prefetch)
    for (int it = 0; it < QPW - 4; it += 4) {
        acc += do_slot<true>(A0, B0, t0, qb + it + 4, in4, targets, cls_w, P, lane, g, q16, jb);
        acc += do_slot<true>(A1, B1, t1, qb + it + 5, in4, targets, cls_w, P, lane, g, q16, jb);
        acc += do_slot<true>(A2, B2, t2, qb + it + 6, in4, targets, cls_w, P, lane, g, q16, jb);
        acc += do_slot<true>(A3, B3, t3, qb + it + 7, in4, targets, cls_w, P, lane, g, q16, jb);
    }
    acc += do_slot<false>(A0, B0, t0, 0, in4, targets, cls_w, P, lane, g, q16, jb);
    acc += do_slot<false>(A1, B1, t1, 0, in4, targets, cls_w, P, lane, g, q16, jb);
    acc += do_slot<false>(A2, B2, t2, 0, in4, targets, cls_w, P, lane, g, q16, jb);
    acc += do_slot<false>(A3, B3, t3, 0, in4, targets, cls_w, P, lane, g, q16, jb);

    // full-wave reduce (rows already folded; mixing lanes is fine now)
    #pragma unroll
    for (int off = 32; off > 0; off >>= 1)
        acc += __shfl_xor(acc, off, 64);

    __shared__ float ssum[WPB];
    if (lane == 0) ssum[wib] = acc;
    __syncthreads();
    if (tid == 0) {
        float s = 0.0f;
        #pragma unroll
        for (int w = 0; w < WPB; ++w) s += ssum[w];
        partial[blockIdx.x] = s;
    }
}

__global__ __launch_bounds__(256) void focal_final(
    const float* __restrict__ partial, float* __restrict__ out)
{
    double s = 0.0;
    for (int i = threadIdx.x; i < GRID; i += 256) s += (double)partial[i];

    #pragma unroll
    for (int off = 32; off > 0; off >>= 1)
        s += __shfl_xor(s, off, 64);

    __shared__ double sh[4];
    const int wave = threadIdx.x >> 6;
    if ((threadIdx.x & 63) == 0) sh[wave] = s;
    __syncthreads();
    if (threadIdx.x == 0) {
        double tot = sh[0] + sh[1] + sh[2] + sh[3];
        out[0] = (float)(tot / (double)NROWS);
    }
}

extern "C" void kernel_launch(void* const* d_in, const int* in_sizes, int n_in,
                              void* d_out, int out_size, void* d_ws, size_t ws_size,
                              hipStream_t stream) {
    const float* inputs  = (const float*)d_in[0];
    const int*   targets = (const int*)  d_in[1];
    const float* cls_w   = (const float*)d_in[2];
    const float* P       = (const float*)d_in[3];
    float* out     = (float*)d_out;
    float* partial = (float*)d_ws;   // GRID floats = 16 KiB

    focal_main<<<GRID, BLOCK, 0, stream>>>(inputs, targets, cls_w, P, partial);
    focal_final<<<1, 256, 0, stream>>>(partial, out);
}

// Round 4
// 698.861 us; speedup vs baseline: 1.0056x; 1.0056x over previous
//
#include <hip/hip_runtime.h>

// ConfusionAwareFocalLoss: N=1048576 rows, C=128 classes, gamma=2, smoothing=0.1
// loss_i = cw[t] * sum_j -(1-p_j)^2 * (0.1/128 + 0.9*[j==t]) * logp_j
//        + sum_j max(P[t,j]-1, 0) * p_j          (P diag == 1 -> term 0)
// out = mean_i loss_i
//
// R4: occupancy-forcing discriminator. Three structurally different kernels all
// landed at 693-703 us total; latency arithmetic shows focal_main cannot exceed
// ~130-150 us at >=1 wave/SIMD, so either occupancy is degenerate or the total
// is harness-floor-dominated. This round: __launch_bounds__(256,8) caps VGPR at
// 64 and forces 8 waves/SIMD; GRID=2048 x 4 waves = 8192 waves = exact machine
// fill (no tail); depth-1 modulo prefetch (lean VGPR), scatter loads issued
// first, DPP row reductions. Null result => harness floor => ROOFLINE.

#define NROWS 1048576
#define NCLS  128
#define BLOCK 256
#define GRID  2048

#define WPB    (BLOCK / 64)          // waves per block = 4
#define NWAVES (GRID * WPB)          // 8192 = 256 CU x 32 waves/CU (exact fill)
#define NQUADS (NROWS / 4)           // 262144 (4 rows per wave-slot)
#define QPW    (NQUADS / NWAVES)     // 32 slots per wave, exact

constexpr float SMOOTH_OFF = 0.1f / 128.0f;
constexpr float SMOOTH_ON  = 0.9f;   // extra weight on the target column

using f4 = __attribute__((ext_vector_type(4))) float;

// ---- DPP all-reduce within each 16-lane row-group (VALU pipe, no LDS) ----
// row_ror:N ctrl = 0x120|N. 8/4/2/1 circulant doubling leaves every lane
// holding the full 16-lane reduction.
template <int CTRL>
__device__ __forceinline__ float row_rot(float v) {
    int r = __builtin_amdgcn_update_dpp(__float_as_int(v), __float_as_int(v),
                                        CTRL, 0xF, 0xF, false);
    return __int_as_float(r);
}
__device__ __forceinline__ float grpmax16(float v) {
    v = fmaxf(v, row_rot<0x128>(v));   // row_ror:8
    v = fmaxf(v, row_rot<0x124>(v));   // row_ror:4
    v = fmaxf(v, row_rot<0x122>(v));   // row_ror:2
    v = fmaxf(v, row_rot<0x121>(v));   // row_ror:1
    return v;
}
__device__ __forceinline__ float grpsum16(float v) {
    v += row_rot<0x128>(v);
    v += row_rot<0x124>(v);
    v += row_rot<0x122>(v);
    v += row_rot<0x121>(v);
    return v;
}

// Compute one quad-slot given already-loaded inputs + P-row fragments.
__device__ __forceinline__ float slot_compute(
    const f4 Ac, const f4 Bc, const int tc,
    const f4 pa, const f4 pb, const float cw, const int jb)
{
    // row max over 128 = 16 lanes x 8 elems (one DPP chain serves all 4 rows)
    float m = fmaxf(fmaxf(fmaxf(Ac[0], Ac[1]), fmaxf(Ac[2], Ac[3])),
                    fmaxf(fmaxf(Bc[0], Bc[1]), fmaxf(Bc[2], Bc[3])));
    m = grpmax16(m);

    float ev[8];
    #pragma unroll
    for (int k = 0; k < 4; ++k) ev[k]     = __expf(Ac[k] - m);
    #pragma unroll
    for (int k = 0; k < 4; ++k) ev[4 + k] = __expf(Bc[k] - m);

    float z = ((ev[0] + ev[1]) + (ev[2] + ev[3]))
            + ((ev[4] + ev[5]) + (ev[6] + ev[7]));
    z = grpsum16(z);

    const float mlz = m + __logf(z);     // x - mlz = log_softmax
    const float rZ  = 1.0f / z;

    float s1 = 0.0f, te = 0.0f, pen = 0.0f;
    #pragma unroll
    for (int k = 0; k < 8; ++k) {
        const float x   = (k < 4) ? Ac[k] : Bc[k - 4];
        const float pvk = (k < 4) ? pa[k] : pb[k - 4];
        const float lp  = x - mlz;           // log prob
        const float p   = ev[k] * rZ;        // prob
        const float om  = 1.0f - p;
        const float fl  = om * om * lp;      // focal-weighted log prob
        s1  += fl;
        if (jb + k == tc) te = fl;           // target column
        pen += fmaxf(pvk - 1.0f, 0.0f) * p;  // confusion penalty
    }
    return pen - cw * (SMOOTH_OFF * s1 + SMOOTH_ON * te);
}

__global__ __launch_bounds__(BLOCK, 8) void focal_main(
    const float* __restrict__ inputs,     // [N, 128]
    const int*   __restrict__ targets,    // [N]
    const float* __restrict__ cls_w,      // [128]
    const float* __restrict__ P,          // [128, 128]
    float*       __restrict__ partial)    // [GRID]
{
    const int tid  = threadIdx.x;
    const int lane = tid & 63;
    const int wib  = tid >> 6;            // wave in block (0..3)
    const int g    = lane >> 4;           // row within quad (0..3)
    const int q16  = lane & 15;           // lane within 16-lane row-group
    const int jb   = q16 * 8;             // first class index this lane owns

    const int waveId = blockIdx.x * WPB + wib;
    const f4* in4 = reinterpret_cast<const f4*>(inputs);

    const int qb = waveId * QPW;          // contiguous 32-quad (64 KiB) range

    // prologue: slot 0 in flight
    f4 A = __builtin_nontemporal_load(in4 + (size_t)qb * 128 + lane * 2);
    f4 B = __builtin_nontemporal_load(in4 + (size_t)qb * 128 + lane * 2 + 1);
    int t = targets[qb * 4 + g];

    float acc = 0.0f;

    for (int it = 0; it < QPW - 1; ++it) {
        // scatter loads for CURRENT target first (L1/L2-resident);
        // waiting on these must not drain the streaming loads behind them
        const float cw = cls_w[t];
        const f4* prow = reinterpret_cast<const f4*>(P + (size_t)t * NCLS);
        const f4 pa = prow[2 * q16];
        const f4 pb = prow[2 * q16 + 1];

        // then issue NEXT slot's stream (consumed next iteration; renames, no copies)
        const int qn = qb + it + 1;
        const f4  An = __builtin_nontemporal_load(in4 + (size_t)qn * 128 + lane * 2);
        const f4  Bn = __builtin_nontemporal_load(in4 + (size_t)qn * 128 + lane * 2 + 1);
        const int tn = targets[qn * 4 + g];

        acc += slot_compute(A, B, t, pa, pb, cw, jb);

        A = An; B = Bn; t = tn;
    }
    {   // last slot (no prefetch)
        const float cw = cls_w[t];
        const f4* prow = reinterpret_cast<const f4*>(P + (size_t)t * NCLS);
        const f4 pa = prow[2 * q16];
        const f4 pb = prow[2 * q16 + 1];
        acc += slot_compute(A, B, t, pa, pb, cw, jb);
    }

    // full-wave reduce (rows already folded; mixing lanes is fine now)
    #pragma unroll
    for (int off = 32; off > 0; off >>= 1)
        acc += __shfl_xor(acc, off, 64);

    __shared__ float ssum[WPB];
    if (lane == 0) ssum[wib] = acc;
    __syncthreads();
    if (tid == 0) {
        float s = 0.0f;
        #pragma unroll
        for (int w = 0; w < WPB; ++w) s += ssum[w];
        partial[blockIdx.x] = s;
    }
}

__global__ __launch_bounds__(256) void focal_final(
    const float* __restrict__ partial, float* __restrict__ out)
{
    double s = 0.0;
    for (int i = threadIdx.x; i < GRID; i += 256) s += (double)partial[i];

    #pragma unroll
    for (int off = 32; off > 0; off >>= 1)
        s += __shfl_xor(s, off, 64);

    __shared__ double sh[4];
    const int wave = threadIdx.x >> 6;
    if ((threadIdx.x & 63) == 0) sh[wave] = s;
    __syncthreads();
    if (threadIdx.x == 0) {
        double tot = sh[0] + sh[1] + sh[2] + sh[3];
        out[0] = (float)(tot / (double)NROWS);
    }
}

extern "C" void kernel_launch(void* const* d_in, const int* in_sizes, int n_in,
                              void* d_out, int out_size, void* d_ws, size_t ws_size,
                              hipStream_t stream) {
    const float* inputs  = (const float*)d_in[0];
    const int*   targets = (const int*)  d_in[1];
    const float* cls_w   = (const float*)d_in[2];
    const float* P       = (const float*)d_in[3];
    float* out     = (float*)d_out;
    float* partial = (float*)d_ws;   // GRID floats = 8 KiB

    focal_main<<<GRID, BLOCK, 0, stream>>>(inputs, targets, cls_w, P, partial);
    focal_final<<<1, 256, 0, stream>>>(partial, out);
}